// Round 1
// baseline (849.571 us; speedup 1.0000x reference)
//
#include <hip/hip_runtime.h>

#define EPSF 1e-6f

constexpr int BB   = 8;
constexpr int BINS = 2048;
constexpr int HW   = 2048 * 2048;
constexpr int NTOT = BB * HW;              // 33,554,432
constexpr float DELTA = 1.0f / BINS;       // exact power of 2

// ---------- helpers ----------
__device__ __forceinline__ unsigned fkey(float f) {
  unsigned b = __float_as_uint(f);
  return (b & 0x80000000u) ? ~b : (b | 0x80000000u);   // order-preserving map
}
__device__ __forceinline__ float fdec(unsigned k) {
  return (k & 0x80000000u) ? __uint_as_float(k & 0x7FFFFFFFu)
                           : __uint_as_float(~k);
}

__device__ __forceinline__ float wred_sum(float v) {
  #pragma unroll
  for (int o = 32; o > 0; o >>= 1) v += __shfl_down(v, o);
  return v;
}
__device__ __forceinline__ float wred_min(float v) {
  #pragma unroll
  for (int o = 32; o > 0; o >>= 1) v = fminf(v, __shfl_down(v, o));
  return v;
}
__device__ __forceinline__ float wred_max(float v) {
  #pragma unroll
  for (int o = 32; o > 0; o >>= 1) v = fmaxf(v, __shfl_down(v, o));
  return v;
}
__device__ __forceinline__ double wred_sumd(double v) {
  #pragma unroll
  for (int o = 32; o > 0; o >>= 1) v += __shfl_down(v, o);
  return v;
}

// ---------- kernel 0: init workspace ----------
__global__ void init_ws(unsigned* keys, double* partaSum, float* hists) {
  int i = blockIdx.x * blockDim.x + threadIdx.x;
  if (i == 0) {
    keys[0] = 0xFFFFFFFFu; keys[1] = 0u;   // input min/max keys
    keys[2] = 0xFFFFFFFFu; keys[3] = 0u;   // target min/max keys
    partaSum[0] = 0.0;
  }
  int stride = gridDim.x * blockDim.x;
  for (int j = i; j < 2 * BB * BINS; j += stride) hists[j] = 0.0f;
}

// ---------- kernel 1: fused minmax + part-A sum ----------
__global__ __launch_bounds__(256) void pass1(
    const float4* __restrict__ inp, const float4* __restrict__ tgt,
    const float4* __restrict__ we1, unsigned* keys, double* partaSum) {
  int idx = blockIdx.x * blockDim.x + threadIdx.x;
  int stride = gridDim.x * blockDim.x;
  const int nvec = NTOT / 4;

  float mnI = INFINITY, mxI = -INFINITY;
  float mnT = INFINITY, mxT = -INFINITY;
  float acc = 0.0f;

  for (int i = idx; i < nvec; i += stride) {
    float4 a = inp[i];
    float4 t = tgt[i];
    float4 w = we1[i];
    #define PART_A(ax, tx, wx)                                   \
      {                                                          \
        mnI = fminf(mnI, ax); mxI = fmaxf(mxI, ax);              \
        mnT = fminf(mnT, tx); mxT = fmaxf(mxT, tx);              \
        float l1 = fabsf((ax) - (tx));                           \
        float wk = (wx) + EPSF;                                  \
        acc += l1 * wk + l1 / wk;                                \
      }
    PART_A(a.x, t.x, w.x)
    PART_A(a.y, t.y, w.y)
    PART_A(a.z, t.z, w.z)
    PART_A(a.w, t.w, w.w)
    #undef PART_A
  }

  // wave reduce
  mnI = wred_min(mnI); mxI = wred_max(mxI);
  mnT = wred_min(mnT); mxT = wred_max(mxT);
  float ws_ = wred_sum(acc);

  __shared__ float sMnI[4], sMxI[4], sMnT[4], sMxT[4];
  __shared__ double sAcc[4];
  int wave = threadIdx.x >> 6, lane = threadIdx.x & 63;
  if (lane == 0) {
    sMnI[wave] = mnI; sMxI[wave] = mxI;
    sMnT[wave] = mnT; sMxT[wave] = mxT;
    sAcc[wave] = (double)ws_;
  }
  __syncthreads();
  if (threadIdx.x == 0) {
    float bMnI = sMnI[0], bMxI = sMxI[0], bMnT = sMnT[0], bMxT = sMxT[0];
    double bAcc = sAcc[0];
    #pragma unroll
    for (int i = 1; i < 4; ++i) {
      bMnI = fminf(bMnI, sMnI[i]); bMxI = fmaxf(bMxI, sMxI[i]);
      bMnT = fminf(bMnT, sMnT[i]); bMxT = fmaxf(bMxT, sMxT[i]);
      bAcc += sAcc[i];
    }
    atomicMin(&keys[0], fkey(bMnI));
    atomicMax(&keys[1], fkey(bMxI));
    atomicMin(&keys[2], fkey(bMnT));
    atomicMax(&keys[3], fkey(bMxT));
    atomicAdd(partaSum, bAcc);
  }
}

// ---------- kernel 2: per-image soft histograms ----------
__device__ __forceinline__ void hist_add(float x, float mn, float inv,
                                         float* __restrict__ h) {
  float xn = (x - mn) * inv;
  int k = (int)floorf(xn * (float)BINS);
  k = max(0, min(BINS - 1, k));
  float lower = (float)k * DELTA;
  if (k >= 1 && k <= BINS - 2) atomicAdd(&h[k], (lower + DELTA) - xn);
  if (k <= BINS - 3) atomicAdd(&h[k + 1], xn - lower);
}

__global__ __launch_bounds__(256) void hist_pass(
    const float4* __restrict__ inp, const float4* __restrict__ tgt,
    const unsigned* __restrict__ keys,
    float* __restrict__ predRaw, float* __restrict__ gtRaw) {
  __shared__ float hp[BINS];
  __shared__ float hg[BINS];
  const int b = blockIdx.y;

  for (int j = threadIdx.x; j < BINS; j += blockDim.x) { hp[j] = 0.0f; hg[j] = 0.0f; }
  __syncthreads();

  const float mnI = fdec(keys[0]);
  const float invI = 1.0f / (fdec(keys[1]) - mnI);
  const float mnT = fdec(keys[2]);
  const float invT = 1.0f / (fdec(keys[3]) - mnT);

  const int nvec = HW / 4;
  const float4* ib = inp + (size_t)b * nvec;
  const float4* tb = tgt + (size_t)b * nvec;
  int stride = gridDim.x * blockDim.x;
  for (int i = blockIdx.x * blockDim.x + threadIdx.x; i < nvec; i += stride) {
    float4 a = ib[i];
    float4 t = tb[i];
    hist_add(a.x, mnI, invI, hp);
    hist_add(a.y, mnI, invI, hp);
    hist_add(a.z, mnI, invI, hp);
    hist_add(a.w, mnI, invI, hp);
    hist_add(t.x, mnT, invT, hg);
    hist_add(t.y, mnT, invT, hg);
    hist_add(t.z, mnT, invT, hg);
    hist_add(t.w, mnT, invT, hg);
  }
  __syncthreads();

  for (int j = threadIdx.x; j < BINS; j += blockDim.x) {
    float vp = hp[j], vg = hg[j];
    if (vp != 0.0f) atomicAdd(&predRaw[b * BINS + j], vp);
    if (vg != 0.0f) atomicAdd(&gtRaw[b * BINS + j], vg);
  }
}

// ---------- kernel 3: normalize hists, KL term, final scalar ----------
__global__ __launch_bounds__(1024) void finalize_k(
    const float* __restrict__ predRaw, const float* __restrict__ gtRaw,
    const float* __restrict__ we2, const double* __restrict__ partaSum,
    float* __restrict__ out) {
  __shared__ double swp[16], swg[16];
  __shared__ double bc[2];
  const int tid = threadIdx.x;
  const int wave = tid >> 6, lane = tid & 63;
  const int M = BB * BINS;  // 16384

  double sp = 0.0, sg = 0.0;
  for (int i = tid; i < M; i += 1024) { sp += (double)predRaw[i]; sg += (double)gtRaw[i]; }
  sp = wred_sumd(sp);
  sg = wred_sumd(sg);
  if (lane == 0) { swp[wave] = sp; swg[wave] = sg; }
  __syncthreads();
  if (tid == 0) {
    double a = 0.0, b = 0.0;
    #pragma unroll
    for (int i = 0; i < 16; ++i) { a += swp[i]; b += swg[i]; }
    bc[0] = a; bc[1] = b;
  }
  __syncthreads();
  const float sumP = (float)bc[0];
  const float sumG = (float)bc[1];

  double pb = 0.0;
  for (int i = tid; i < M; i += 1024) {
    float p = predRaw[i] / sumP;
    float g = gtRaw[i] / sumG;
    float kld = fabsf(expf(g) * (g - p));
    float w2v = we2[i] + EPSF;
    pb += (double)(kld * w2v + kld / w2v);
  }
  pb = wred_sumd(pb);
  if (lane == 0) swp[wave] = pb;
  __syncthreads();
  if (tid == 0) {
    double s = 0.0;
    #pragma unroll
    for (int i = 0; i < 16; ++i) s += swp[i];
    double parta = partaSum[0] / (double)NTOT;
    double partb = s / (double)M;
    out[0] = (float)(4.0 * parta + partb);
  }
}

extern "C" void kernel_launch(void* const* d_in, const int* in_sizes, int n_in,
                              void* d_out, int out_size, void* d_ws, size_t ws_size,
                              hipStream_t stream) {
  const float* inputo = (const float*)d_in[0];
  const float* target = (const float*)d_in[1];
  const float* we1    = (const float*)d_in[2];
  const float* we2    = (const float*)d_in[3];
  float* out = (float*)d_out;

  char* ws = (char*)d_ws;
  unsigned* keys    = (unsigned*)ws;            // 4 × u32
  double*  partaSum = (double*)(ws + 16);       // 1 × f64
  float*   predRaw  = (float*)(ws + 64);        // BB*BINS floats
  float*   gtRaw    = (float*)(ws + 64 + BB * BINS * 4);

  init_ws<<<64, 256, 0, stream>>>(keys, partaSum, predRaw);  // hists contiguous

  pass1<<<2048, 256, 0, stream>>>((const float4*)inputo, (const float4*)target,
                                  (const float4*)we1, keys, partaSum);

  dim3 g2(256, BB);
  hist_pass<<<g2, 256, 0, stream>>>((const float4*)inputo, (const float4*)target,
                                    keys, predRaw, gtRaw);

  finalize_k<<<1, 1024, 0, stream>>>(predRaw, gtRaw, we2, partaSum, out);
}

// Round 2
// 234.149 us; speedup vs baseline: 3.6283x; 3.6283x over previous
//
#include <hip/hip_runtime.h>

#define EPSF 1e-6f

constexpr int BB   = 8;
constexpr int BINS = 2048;
constexpr int HW   = 2048 * 2048;
constexpr int NTOT = BB * HW;              // 33,554,432
constexpr float QSCALE = 262144.0f;        // 2^18 fixed-point scale
constexpr unsigned QONE = 262144u;

typedef float f4v __attribute__((ext_vector_type(4)));

// ---------- helpers ----------
__device__ __forceinline__ unsigned fkey(float f) {
  unsigned b = __float_as_uint(f);
  return (b & 0x80000000u) ? ~b : (b | 0x80000000u);   // order-preserving map
}
__device__ __forceinline__ float fdec(unsigned k) {
  return (k & 0x80000000u) ? __uint_as_float(k & 0x7FFFFFFFu)
                           : __uint_as_float(~k);
}

__device__ __forceinline__ float wred_sum(float v) {
  #pragma unroll
  for (int o = 32; o > 0; o >>= 1) v += __shfl_down(v, o);
  return v;
}
__device__ __forceinline__ float wred_min(float v) {
  #pragma unroll
  for (int o = 32; o > 0; o >>= 1) v = fminf(v, __shfl_down(v, o));
  return v;
}
__device__ __forceinline__ float wred_max(float v) {
  #pragma unroll
  for (int o = 32; o > 0; o >>= 1) v = fmaxf(v, __shfl_down(v, o));
  return v;
}
__device__ __forceinline__ double wred_sumd(double v) {
  #pragma unroll
  for (int o = 32; o > 0; o >>= 1) v += __shfl_down(v, o);
  return v;
}

// ---------- kernel 0: init workspace ----------
__global__ void init_ws(unsigned* keys, double* partaSum, unsigned* hists) {
  int i = blockIdx.x * blockDim.x + threadIdx.x;
  if (i == 0) {
    keys[0] = 0xFFFFFFFFu; keys[1] = 0u;   // input min/max keys
    keys[2] = 0xFFFFFFFFu; keys[3] = 0u;   // target min/max keys
    partaSum[0] = 0.0;
  }
  int stride = gridDim.x * blockDim.x;
  for (int j = i; j < 2 * BB * BINS; j += stride) hists[j] = 0u;
}

// ---------- kernel 1: fused minmax + part-A sum ----------
__global__ __launch_bounds__(256) void pass1(
    const float4* __restrict__ inp, const float4* __restrict__ tgt,
    const f4v* __restrict__ we1, unsigned* keys, double* partaSum) {
  int idx = blockIdx.x * blockDim.x + threadIdx.x;
  int stride = gridDim.x * blockDim.x;
  const int nvec = NTOT / 4;

  float mnI = INFINITY, mxI = -INFINITY;
  float mnT = INFINITY, mxT = -INFINITY;
  float acc = 0.0f;

  for (int i = idx; i < nvec; i += stride) {
    float4 a = inp[i];
    float4 t = tgt[i];
    f4v w = __builtin_nontemporal_load(&we1[i]);   // streamed once, keep L3 for inp/tgt
    #define PART_A(ax, tx, wx)                                   \
      {                                                          \
        mnI = fminf(mnI, ax); mxI = fmaxf(mxI, ax);              \
        mnT = fminf(mnT, tx); mxT = fmaxf(mxT, tx);              \
        float l1 = fabsf((ax) - (tx));                           \
        float wk = (wx) + EPSF;                                  \
        acc += l1 * wk + l1 / wk;                                \
      }
    PART_A(a.x, t.x, w.x)
    PART_A(a.y, t.y, w.y)
    PART_A(a.z, t.z, w.z)
    PART_A(a.w, t.w, w.w)
    #undef PART_A
  }

  mnI = wred_min(mnI); mxI = wred_max(mxI);
  mnT = wred_min(mnT); mxT = wred_max(mxT);
  float ws_ = wred_sum(acc);

  __shared__ float sMnI[4], sMxI[4], sMnT[4], sMxT[4];
  __shared__ double sAcc[4];
  int wave = threadIdx.x >> 6, lane = threadIdx.x & 63;
  if (lane == 0) {
    sMnI[wave] = mnI; sMxI[wave] = mxI;
    sMnT[wave] = mnT; sMxT[wave] = mxT;
    sAcc[wave] = (double)ws_;
  }
  __syncthreads();
  if (threadIdx.x == 0) {
    float bMnI = sMnI[0], bMxI = sMxI[0], bMnT = sMnT[0], bMxT = sMxT[0];
    double bAcc = sAcc[0];
    #pragma unroll
    for (int i = 1; i < 4; ++i) {
      bMnI = fminf(bMnI, sMnI[i]); bMxI = fmaxf(bMxI, sMxI[i]);
      bMnT = fminf(bMnT, sMnT[i]); bMxT = fmaxf(bMxT, sMxT[i]);
      bAcc += sAcc[i];
    }
    atomicMin(&keys[0], fkey(bMnI));
    atomicMax(&keys[1], fkey(bMxI));
    atomicMin(&keys[2], fkey(bMnT));
    atomicMax(&keys[3], fkey(bMxT));
    atomicAdd(partaSum, bAcc);
  }
}

// ---------- kernel 2: per-image soft histograms (u32 fixed-point) ----------
__global__ __launch_bounds__(256) void hist_pass(
    const float4* __restrict__ inp, const float4* __restrict__ tgt,
    const unsigned* __restrict__ keys,
    unsigned* __restrict__ predRaw, unsigned* __restrict__ gtRaw) {
  __shared__ unsigned hp[BINS];
  __shared__ unsigned hg[BINS];
  const int b = blockIdx.y;

  for (int j = threadIdx.x; j < BINS; j += blockDim.x) { hp[j] = 0u; hg[j] = 0u; }
  __syncthreads();

  const float mnI = fdec(keys[0]);
  const float invI = (float)BINS / (fdec(keys[1]) - mnI);  // fold xBINS
  const float mnT = fdec(keys[2]);
  const float invT = (float)BINS / (fdec(keys[3]) - mnT);

  // hist_add on the shared arrays directly so address-space inference
  // yields native ds_add_u32 (NOT a flat/CAS float loop).
  #define HIST_ADD(x, mn, inv, h)                                  \
    {                                                              \
      float t_ = ((x) - (mn)) * (inv);                             \
      int k_ = (int)floorf(t_);                                    \
      k_ = max(0, min(BINS - 1, k_));                              \
      float frac_ = t_ - (float)k_;                                \
      unsigned q_ = (unsigned)(frac_ * QSCALE + 0.5f);             \
      if (k_ >= 1 && k_ <= BINS - 2) atomicAdd(&h[k_], QONE - q_); \
      if (k_ <= BINS - 3) atomicAdd(&h[k_ + 1], q_);               \
    }

  const int nvec = HW / 4;
  const float4* ib = inp + (size_t)b * nvec;
  const float4* tb = tgt + (size_t)b * nvec;
  int stride = gridDim.x * blockDim.x;
  for (int i = blockIdx.x * blockDim.x + threadIdx.x; i < nvec; i += stride) {
    float4 a = ib[i];
    float4 t = tb[i];
    HIST_ADD(a.x, mnI, invI, hp)
    HIST_ADD(a.y, mnI, invI, hp)
    HIST_ADD(a.z, mnI, invI, hp)
    HIST_ADD(a.w, mnI, invI, hp)
    HIST_ADD(t.x, mnT, invT, hg)
    HIST_ADD(t.y, mnT, invT, hg)
    HIST_ADD(t.z, mnT, invT, hg)
    HIST_ADD(t.w, mnT, invT, hg)
  }
  #undef HIST_ADD
  __syncthreads();

  for (int j = threadIdx.x; j < BINS; j += blockDim.x) {
    unsigned vp = hp[j], vg = hg[j];
    if (vp) atomicAdd(&predRaw[b * BINS + j], vp);
    if (vg) atomicAdd(&gtRaw[b * BINS + j], vg);
  }
}

// ---------- kernel 3: normalize hists, KL term, final scalar ----------
__global__ __launch_bounds__(1024) void finalize_k(
    const unsigned* __restrict__ predRaw, const unsigned* __restrict__ gtRaw,
    const float* __restrict__ we2, const double* __restrict__ partaSum,
    float* __restrict__ out) {
  __shared__ double swp[16], swg[16];
  __shared__ double bc[2];
  const int tid = threadIdx.x;
  const int wave = tid >> 6, lane = tid & 63;
  const int M = BB * BINS;  // 16384
  const double invq = 1.0 / (double)QONE;

  double sp = 0.0, sg = 0.0;
  for (int i = tid; i < M; i += 1024) {
    sp += (double)predRaw[i];
    sg += (double)gtRaw[i];
  }
  sp = wred_sumd(sp);
  sg = wred_sumd(sg);
  if (lane == 0) { swp[wave] = sp; swg[wave] = sg; }
  __syncthreads();
  if (tid == 0) {
    double a = 0.0, b = 0.0;
    #pragma unroll
    for (int i = 0; i < 16; ++i) { a += swp[i]; b += swg[i]; }
    bc[0] = a; bc[1] = b;     // sums in fixed-point units (scale cancels)
  }
  __syncthreads();
  const float sumP = (float)(bc[0] * invq);
  const float sumG = (float)(bc[1] * invq);

  double pb = 0.0;
  for (int i = tid; i < M; i += 1024) {
    float p = (float)((double)predRaw[i] * invq) / sumP;
    float g = (float)((double)gtRaw[i] * invq) / sumG;
    float kld = fabsf(expf(g) * (g - p));
    float w2v = we2[i] + EPSF;
    pb += (double)(kld * w2v + kld / w2v);
  }
  pb = wred_sumd(pb);
  if (lane == 0) swp[wave] = pb;
  __syncthreads();
  if (tid == 0) {
    double s = 0.0;
    #pragma unroll
    for (int i = 0; i < 16; ++i) s += swp[i];
    double parta = partaSum[0] / (double)NTOT;
    double partb = s / (double)M;
    out[0] = (float)(4.0 * parta + partb);
  }
}

extern "C" void kernel_launch(void* const* d_in, const int* in_sizes, int n_in,
                              void* d_out, int out_size, void* d_ws, size_t ws_size,
                              hipStream_t stream) {
  const float* inputo = (const float*)d_in[0];
  const float* target = (const float*)d_in[1];
  const float* we1    = (const float*)d_in[2];
  const float* we2    = (const float*)d_in[3];
  float* out = (float*)d_out;

  char* ws = (char*)d_ws;
  unsigned* keys    = (unsigned*)ws;            // 4 x u32
  double*  partaSum = (double*)(ws + 16);       // 1 x f64
  unsigned* predRaw = (unsigned*)(ws + 64);     // BB*BINS u32
  unsigned* gtRaw   = (unsigned*)(ws + 64 + BB * BINS * 4);

  init_ws<<<64, 256, 0, stream>>>(keys, partaSum, predRaw);  // hists contiguous

  pass1<<<2048, 256, 0, stream>>>((const float4*)inputo, (const float4*)target,
                                  (const f4v*)we1, keys, partaSum);

  dim3 g2(256, BB);
  hist_pass<<<g2, 256, 0, stream>>>((const float4*)inputo, (const float4*)target,
                                    keys, predRaw, gtRaw);

  finalize_k<<<1, 1024, 0, stream>>>(predRaw, gtRaw, we2, partaSum, out);
}

// Round 3
// 223.907 us; speedup vs baseline: 3.7943x; 1.0457x over previous
//
#include <hip/hip_runtime.h>

#define EPSF 1e-6f

constexpr int BB   = 8;
constexpr int BINS = 2048;
constexpr int HW   = 2048 * 2048;
constexpr int NTOT = BB * HW;              // 33,554,432
constexpr float QSCALE = 262144.0f;        // 2^18 fixed-point scale
constexpr unsigned QONE = 262144u;

typedef float f4v __attribute__((ext_vector_type(4)));

// ---------- helpers ----------
__device__ __forceinline__ unsigned fkey(float f) {
  unsigned b = __float_as_uint(f);
  return (b & 0x80000000u) ? ~b : (b | 0x80000000u);   // order-preserving map
}
__device__ __forceinline__ float fdec(unsigned k) {
  return (k & 0x80000000u) ? __uint_as_float(k & 0x7FFFFFFFu)
                           : __uint_as_float(~k);
}

__device__ __forceinline__ float wred_sum(float v) {
  #pragma unroll
  for (int o = 32; o > 0; o >>= 1) v += __shfl_down(v, o);
  return v;
}
__device__ __forceinline__ float wred_min(float v) {
  #pragma unroll
  for (int o = 32; o > 0; o >>= 1) v = fminf(v, __shfl_down(v, o));
  return v;
}
__device__ __forceinline__ float wred_max(float v) {
  #pragma unroll
  for (int o = 32; o > 0; o >>= 1) v = fmaxf(v, __shfl_down(v, o));
  return v;
}
__device__ __forceinline__ double wred_sumd(double v) {
  #pragma unroll
  for (int o = 32; o > 0; o >>= 1) v += __shfl_down(v, o);
  return v;
}

// ---------- kernel 0: init workspace ----------
__global__ void init_ws(unsigned* keys, double* partaSum, unsigned* hists) {
  int i = blockIdx.x * blockDim.x + threadIdx.x;
  if (i == 0) {
    keys[0] = 0xFFFFFFFFu; keys[1] = 0u;   // input min/max keys
    keys[2] = 0xFFFFFFFFu; keys[3] = 0u;   // target min/max keys
    partaSum[0] = 0.0;
  }
  int stride = gridDim.x * blockDim.x;
  for (int j = i; j < 2 * BB * BINS; j += stride) hists[j] = 0u;
}

// ---------- kernel 1: fused minmax + part-A sum (4x stride-unroll, MLP) ----------
__global__ __launch_bounds__(256) void pass1(
    const float4* __restrict__ inp, const float4* __restrict__ tgt,
    const f4v* __restrict__ we1, unsigned* keys, double* partaSum) {
  const int tid = blockIdx.x * blockDim.x + threadIdx.x;
  const int T   = gridDim.x * blockDim.x;        // 524288 threads
  const int nvec = NTOT / 4;                     // 8,388,608 float4 per stream

  float mnI = INFINITY, mxI = -INFINITY;
  float mnT = INFINITY, mxT = -INFINITY;
  float acc = 0.0f;

  // nvec == 16*T exactly (grid fixed at 2048x256): 4 outer iterations,
  // 12 independent coalesced 16B loads in flight per iteration.
  for (int i = tid; i < nvec; i += 4 * T) {
    float4 a0 = inp[i];         float4 a1 = inp[i + T];
    float4 a2 = inp[i + 2 * T]; float4 a3 = inp[i + 3 * T];
    float4 t0 = tgt[i];         float4 t1 = tgt[i + T];
    float4 t2 = tgt[i + 2 * T]; float4 t3 = tgt[i + 3 * T];
    f4v w0 = __builtin_nontemporal_load(&we1[i]);
    f4v w1 = __builtin_nontemporal_load(&we1[i + T]);
    f4v w2 = __builtin_nontemporal_load(&we1[i + 2 * T]);
    f4v w3 = __builtin_nontemporal_load(&we1[i + 3 * T]);

    #define PART_A(ax, tx, wx)                                   \
      {                                                          \
        mnI = fminf(mnI, ax); mxI = fmaxf(mxI, ax);              \
        mnT = fminf(mnT, tx); mxT = fmaxf(mxT, tx);              \
        float l1 = fabsf((ax) - (tx));                           \
        float wk = (wx) + EPSF;                                  \
        float r  = __builtin_amdgcn_rcpf(wk);                    \
        r = r * (2.0f - wk * r);      /* one Newton step */      \
        acc += l1 * (wk + r);                                    \
      }
    PART_A(a0.x, t0.x, w0.x) PART_A(a0.y, t0.y, w0.y)
    PART_A(a0.z, t0.z, w0.z) PART_A(a0.w, t0.w, w0.w)
    PART_A(a1.x, t1.x, w1.x) PART_A(a1.y, t1.y, w1.y)
    PART_A(a1.z, t1.z, w1.z) PART_A(a1.w, t1.w, w1.w)
    PART_A(a2.x, t2.x, w2.x) PART_A(a2.y, t2.y, w2.y)
    PART_A(a2.z, t2.z, w2.z) PART_A(a2.w, t2.w, w2.w)
    PART_A(a3.x, t3.x, w3.x) PART_A(a3.y, t3.y, w3.y)
    PART_A(a3.z, t3.z, w3.z) PART_A(a3.w, t3.w, w3.w)
    #undef PART_A
  }

  mnI = wred_min(mnI); mxI = wred_max(mxI);
  mnT = wred_min(mnT); mxT = wred_max(mxT);
  float ws_ = wred_sum(acc);

  __shared__ float sMnI[4], sMxI[4], sMnT[4], sMxT[4];
  __shared__ double sAcc[4];
  int wave = threadIdx.x >> 6, lane = threadIdx.x & 63;
  if (lane == 0) {
    sMnI[wave] = mnI; sMxI[wave] = mxI;
    sMnT[wave] = mnT; sMxT[wave] = mxT;
    sAcc[wave] = (double)ws_;
  }
  __syncthreads();
  if (threadIdx.x == 0) {
    float bMnI = sMnI[0], bMxI = sMxI[0], bMnT = sMnT[0], bMxT = sMxT[0];
    double bAcc = sAcc[0];
    #pragma unroll
    for (int i = 1; i < 4; ++i) {
      bMnI = fminf(bMnI, sMnI[i]); bMxI = fmaxf(bMxI, sMxI[i]);
      bMnT = fminf(bMnT, sMnT[i]); bMxT = fmaxf(bMxT, sMxT[i]);
      bAcc += sAcc[i];
    }
    atomicMin(&keys[0], fkey(bMnI));
    atomicMax(&keys[1], fkey(bMxI));
    atomicMin(&keys[2], fkey(bMnT));
    atomicMax(&keys[3], fkey(bMxT));
    atomicAdd(partaSum, bAcc);
  }
}

// ---------- kernel 2: per-image soft histograms (u32 fixed-point) ----------
__global__ __launch_bounds__(256) void hist_pass(
    const float4* __restrict__ inp, const float4* __restrict__ tgt,
    const unsigned* __restrict__ keys,
    unsigned* __restrict__ predRaw, unsigned* __restrict__ gtRaw) {
  __shared__ unsigned hp[BINS];
  __shared__ unsigned hg[BINS];
  const int b = blockIdx.y;

  for (int j = threadIdx.x; j < BINS; j += blockDim.x) { hp[j] = 0u; hg[j] = 0u; }
  __syncthreads();

  const float mnI = fdec(keys[0]);
  const float invI = (float)BINS / (fdec(keys[1]) - mnI);  // fold xBINS
  const float mnT = fdec(keys[2]);
  const float invT = (float)BINS / (fdec(keys[3]) - mnT);

  #define HIST_ADD(x, mn, inv, h)                                  \
    {                                                              \
      float t_ = ((x) - (mn)) * (inv);                             \
      int k_ = (int)floorf(t_);                                    \
      k_ = max(0, min(BINS - 1, k_));                              \
      float frac_ = t_ - (float)k_;                                \
      unsigned q_ = (unsigned)(frac_ * QSCALE + 0.5f);             \
      if (k_ >= 1 && k_ <= BINS - 2) atomicAdd(&h[k_], QONE - q_); \
      if (k_ <= BINS - 3) atomicAdd(&h[k_ + 1], q_);               \
    }

  const int nvec = HW / 4;
  const float4* ib = inp + (size_t)b * nvec;
  const float4* tb = tgt + (size_t)b * nvec;
  int stride = gridDim.x * blockDim.x;
  for (int i = blockIdx.x * blockDim.x + threadIdx.x; i < nvec; i += stride) {
    float4 a = ib[i];
    float4 t = tb[i];
    HIST_ADD(a.x, mnI, invI, hp)
    HIST_ADD(a.y, mnI, invI, hp)
    HIST_ADD(a.z, mnI, invI, hp)
    HIST_ADD(a.w, mnI, invI, hp)
    HIST_ADD(t.x, mnT, invT, hg)
    HIST_ADD(t.y, mnT, invT, hg)
    HIST_ADD(t.z, mnT, invT, hg)
    HIST_ADD(t.w, mnT, invT, hg)
  }
  #undef HIST_ADD
  __syncthreads();

  for (int j = threadIdx.x; j < BINS; j += blockDim.x) {
    unsigned vp = hp[j], vg = hg[j];
    if (vp) atomicAdd(&predRaw[b * BINS + j], vp);
    if (vg) atomicAdd(&gtRaw[b * BINS + j], vg);
  }
}

// ---------- kernel 3: normalize hists, KL term, final scalar ----------
__global__ __launch_bounds__(1024) void finalize_k(
    const unsigned* __restrict__ predRaw, const unsigned* __restrict__ gtRaw,
    const float* __restrict__ we2, const double* __restrict__ partaSum,
    float* __restrict__ out) {
  __shared__ double swp[16], swg[16];
  __shared__ double bc[2];
  const int tid = threadIdx.x;
  const int wave = tid >> 6, lane = tid & 63;
  const int M = BB * BINS;  // 16384
  const double invq = 1.0 / (double)QONE;

  double sp = 0.0, sg = 0.0;
  for (int i = tid; i < M; i += 1024) {
    sp += (double)predRaw[i];
    sg += (double)gtRaw[i];
  }
  sp = wred_sumd(sp);
  sg = wred_sumd(sg);
  if (lane == 0) { swp[wave] = sp; swg[wave] = sg; }
  __syncthreads();
  if (tid == 0) {
    double a = 0.0, b = 0.0;
    #pragma unroll
    for (int i = 0; i < 16; ++i) { a += swp[i]; b += swg[i]; }
    bc[0] = a; bc[1] = b;     // sums in fixed-point units (scale cancels)
  }
  __syncthreads();
  const float sumP = (float)(bc[0] * invq);
  const float sumG = (float)(bc[1] * invq);

  double pb = 0.0;
  for (int i = tid; i < M; i += 1024) {
    float p = (float)((double)predRaw[i] * invq) / sumP;
    float g = (float)((double)gtRaw[i] * invq) / sumG;
    float kld = fabsf(expf(g) * (g - p));
    float w2v = we2[i] + EPSF;
    pb += (double)(kld * w2v + kld / w2v);
  }
  pb = wred_sumd(pb);
  if (lane == 0) swp[wave] = pb;
  __syncthreads();
  if (tid == 0) {
    double s = 0.0;
    #pragma unroll
    for (int i = 0; i < 16; ++i) s += swp[i];
    double parta = partaSum[0] / (double)NTOT;
    double partb = s / (double)M;
    out[0] = (float)(4.0 * parta + partb);
  }
}

extern "C" void kernel_launch(void* const* d_in, const int* in_sizes, int n_in,
                              void* d_out, int out_size, void* d_ws, size_t ws_size,
                              hipStream_t stream) {
  const float* inputo = (const float*)d_in[0];
  const float* target = (const float*)d_in[1];
  const float* we1    = (const float*)d_in[2];
  const float* we2    = (const float*)d_in[3];
  float* out = (float*)d_out;

  char* ws = (char*)d_ws;
  unsigned* keys    = (unsigned*)ws;            // 4 x u32
  double*  partaSum = (double*)(ws + 16);       // 1 x f64
  unsigned* predRaw = (unsigned*)(ws + 64);     // BB*BINS u32
  unsigned* gtRaw   = (unsigned*)(ws + 64 + BB * BINS * 4);

  init_ws<<<64, 256, 0, stream>>>(keys, partaSum, predRaw);  // hists contiguous

  pass1<<<2048, 256, 0, stream>>>((const float4*)inputo, (const float4*)target,
                                  (const f4v*)we1, keys, partaSum);

  dim3 g2(256, BB);
  hist_pass<<<g2, 256, 0, stream>>>((const float4*)inputo, (const float4*)target,
                                    keys, predRaw, gtRaw);

  finalize_k<<<1, 1024, 0, stream>>>(predRaw, gtRaw, we2, partaSum, out);
}

// Round 4
// 158.195 us; speedup vs baseline: 5.3704x; 1.4154x over previous
//
#include <hip/hip_runtime.h>

#define EPSF 1e-6f

constexpr int BB   = 8;
constexpr int BINS = 2048;
constexpr int HW   = 2048 * 2048;
constexpr int NTOT = BB * HW;              // 33,554,432
constexpr float QSCALE = 262144.0f;        // 2^18 fixed-point scale
constexpr unsigned QONE = 262144u;
constexpr int P1_BLOCKS = 2048;

typedef float f4v __attribute__((ext_vector_type(4)));

// One 64B cache line per block: no false sharing, no atomics.
struct __align__(64) P1Partial {
  float mnI, mxI, mnT, mxT;
  double acc;
};

// ---------- helpers ----------
__device__ __forceinline__ float wred_sum(float v) {
  #pragma unroll
  for (int o = 32; o > 0; o >>= 1) v += __shfl_down(v, o);
  return v;
}
__device__ __forceinline__ float wred_min(float v) {
  #pragma unroll
  for (int o = 32; o > 0; o >>= 1) v = fminf(v, __shfl_down(v, o));
  return v;
}
__device__ __forceinline__ float wred_max(float v) {
  #pragma unroll
  for (int o = 32; o > 0; o >>= 1) v = fmaxf(v, __shfl_down(v, o));
  return v;
}
__device__ __forceinline__ double wred_sumd(double v) {
  #pragma unroll
  for (int o = 32; o > 0; o >>= 1) v += __shfl_down(v, o);
  return v;
}

// ---------- kernel 0: init workspace (zero histograms only) ----------
__global__ void init_ws(unsigned* hists) {
  int i = blockIdx.x * blockDim.x + threadIdx.x;
  int stride = gridDim.x * blockDim.x;
  for (int j = i; j < 2 * BB * BINS; j += stride) hists[j] = 0u;
}

// ---------- kernel 1: fused minmax + part-A sum (no atomics) ----------
__global__ __launch_bounds__(256) void pass1(
    const float4* __restrict__ inp, const float4* __restrict__ tgt,
    const f4v* __restrict__ we1, P1Partial* __restrict__ part) {
  const int tid = blockIdx.x * blockDim.x + threadIdx.x;
  const int T   = gridDim.x * blockDim.x;        // 524288 threads
  const int nvec = NTOT / 4;                     // 8,388,608 float4 per stream

  float mnI = INFINITY, mxI = -INFINITY;
  float mnT = INFINITY, mxT = -INFINITY;
  float acc = 0.0f;

  // nvec == 16*T exactly: 4 outer iterations, 12 independent 16B loads each.
  for (int i = tid; i < nvec; i += 4 * T) {
    float4 a0 = inp[i];         float4 a1 = inp[i + T];
    float4 a2 = inp[i + 2 * T]; float4 a3 = inp[i + 3 * T];
    float4 t0 = tgt[i];         float4 t1 = tgt[i + T];
    float4 t2 = tgt[i + 2 * T]; float4 t3 = tgt[i + 3 * T];
    f4v w0 = __builtin_nontemporal_load(&we1[i]);
    f4v w1 = __builtin_nontemporal_load(&we1[i + T]);
    f4v w2 = __builtin_nontemporal_load(&we1[i + 2 * T]);
    f4v w3 = __builtin_nontemporal_load(&we1[i + 3 * T]);

    #define PART_A(ax, tx, wx)                                   \
      {                                                          \
        mnI = fminf(mnI, ax); mxI = fmaxf(mxI, ax);              \
        mnT = fminf(mnT, tx); mxT = fmaxf(mxT, tx);              \
        float l1 = fabsf((ax) - (tx));                           \
        float wk = (wx) + EPSF;                                  \
        float r  = __builtin_amdgcn_rcpf(wk);                    \
        r = r * (2.0f - wk * r);      /* one Newton step */      \
        acc += l1 * (wk + r);                                    \
      }
    PART_A(a0.x, t0.x, w0.x) PART_A(a0.y, t0.y, w0.y)
    PART_A(a0.z, t0.z, w0.z) PART_A(a0.w, t0.w, w0.w)
    PART_A(a1.x, t1.x, w1.x) PART_A(a1.y, t1.y, w1.y)
    PART_A(a1.z, t1.z, w1.z) PART_A(a1.w, t1.w, w1.w)
    PART_A(a2.x, t2.x, w2.x) PART_A(a2.y, t2.y, w2.y)
    PART_A(a2.z, t2.z, w2.z) PART_A(a2.w, t2.w, w2.w)
    PART_A(a3.x, t3.x, w3.x) PART_A(a3.y, t3.y, w3.y)
    PART_A(a3.z, t3.z, w3.z) PART_A(a3.w, t3.w, w3.w)
    #undef PART_A
  }

  mnI = wred_min(mnI); mxI = wred_max(mxI);
  mnT = wred_min(mnT); mxT = wred_max(mxT);
  float ws_ = wred_sum(acc);

  __shared__ float sMnI[4], sMxI[4], sMnT[4], sMxT[4];
  __shared__ double sAcc[4];
  int wave = threadIdx.x >> 6, lane = threadIdx.x & 63;
  if (lane == 0) {
    sMnI[wave] = mnI; sMxI[wave] = mxI;
    sMnT[wave] = mnT; sMxT[wave] = mxT;
    sAcc[wave] = (double)ws_;
  }
  __syncthreads();
  if (threadIdx.x == 0) {
    float bMnI = sMnI[0], bMxI = sMxI[0], bMnT = sMnT[0], bMxT = sMxT[0];
    double bAcc = sAcc[0];
    #pragma unroll
    for (int i = 1; i < 4; ++i) {
      bMnI = fminf(bMnI, sMnI[i]); bMxI = fmaxf(bMxI, sMxI[i]);
      bMnT = fminf(bMnT, sMnT[i]); bMxT = fmaxf(bMxT, sMxT[i]);
      bAcc += sAcc[i];
    }
    P1Partial p;
    p.mnI = bMnI; p.mxI = bMxI; p.mnT = bMnT; p.mxT = bMxT; p.acc = bAcc;
    part[blockIdx.x] = p;   // plain store to a private cache line
  }
}

// ---------- kernel 1b: reduce the 2048 partials (single block) ----------
__global__ __launch_bounds__(1024) void reduce_p1(
    const P1Partial* __restrict__ part, float* __restrict__ bounds,
    double* __restrict__ partaSum) {
  const int tid = threadIdx.x;
  const int wave = tid >> 6, lane = tid & 63;

  float mnI = INFINITY, mxI = -INFINITY;
  float mnT = INFINITY, mxT = -INFINITY;
  double acc = 0.0;
  for (int i = tid; i < P1_BLOCKS; i += 1024) {
    P1Partial p = part[i];
    mnI = fminf(mnI, p.mnI); mxI = fmaxf(mxI, p.mxI);
    mnT = fminf(mnT, p.mnT); mxT = fmaxf(mxT, p.mxT);
    acc += p.acc;
  }
  mnI = wred_min(mnI); mxI = wred_max(mxI);
  mnT = wred_min(mnT); mxT = wred_max(mxT);
  acc = wred_sumd(acc);

  __shared__ float sMnI[16], sMxI[16], sMnT[16], sMxT[16];
  __shared__ double sAcc[16];
  if (lane == 0) {
    sMnI[wave] = mnI; sMxI[wave] = mxI;
    sMnT[wave] = mnT; sMxT[wave] = mxT;
    sAcc[wave] = acc;
  }
  __syncthreads();
  if (tid == 0) {
    float a = sMnI[0], b = sMxI[0], c = sMnT[0], d = sMxT[0];
    double s = sAcc[0];
    #pragma unroll
    for (int i = 1; i < 16; ++i) {
      a = fminf(a, sMnI[i]); b = fmaxf(b, sMxI[i]);
      c = fminf(c, sMnT[i]); d = fmaxf(d, sMxT[i]);
      s += sAcc[i];
    }
    bounds[0] = a; bounds[1] = b; bounds[2] = c; bounds[3] = d;
    partaSum[0] = s;
  }
}

// ---------- kernel 2: per-image soft histograms (u32 fixed-point) ----------
__global__ __launch_bounds__(256) void hist_pass(
    const float4* __restrict__ inp, const float4* __restrict__ tgt,
    const float* __restrict__ bounds,
    unsigned* __restrict__ predRaw, unsigned* __restrict__ gtRaw) {
  __shared__ unsigned hp[BINS];
  __shared__ unsigned hg[BINS];
  const int b = blockIdx.y;

  for (int j = threadIdx.x; j < BINS; j += blockDim.x) { hp[j] = 0u; hg[j] = 0u; }
  __syncthreads();

  const float mnI = bounds[0];
  const float invI = (float)BINS / (bounds[1] - mnI);  // fold xBINS
  const float mnT = bounds[2];
  const float invT = (float)BINS / (bounds[3] - mnT);

  #define HIST_ADD(x, mn, inv, h)                                  \
    {                                                              \
      float t_ = ((x) - (mn)) * (inv);                             \
      int k_ = (int)floorf(t_);                                    \
      k_ = max(0, min(BINS - 1, k_));                              \
      float frac_ = t_ - (float)k_;                                \
      unsigned q_ = (unsigned)(frac_ * QSCALE + 0.5f);             \
      if (k_ >= 1 && k_ <= BINS - 2) atomicAdd(&h[k_], QONE - q_); \
      if (k_ <= BINS - 3) atomicAdd(&h[k_ + 1], q_);               \
    }

  const int nvec = HW / 4;
  const float4* ib = inp + (size_t)b * nvec;
  const float4* tb = tgt + (size_t)b * nvec;
  int stride = gridDim.x * blockDim.x;
  for (int i = blockIdx.x * blockDim.x + threadIdx.x; i < nvec; i += stride) {
    float4 a = ib[i];
    float4 t = tb[i];
    HIST_ADD(a.x, mnI, invI, hp)
    HIST_ADD(a.y, mnI, invI, hp)
    HIST_ADD(a.z, mnI, invI, hp)
    HIST_ADD(a.w, mnI, invI, hp)
    HIST_ADD(t.x, mnT, invT, hg)
    HIST_ADD(t.y, mnT, invT, hg)
    HIST_ADD(t.z, mnT, invT, hg)
    HIST_ADD(t.w, mnT, invT, hg)
  }
  #undef HIST_ADD
  __syncthreads();

  for (int j = threadIdx.x; j < BINS; j += blockDim.x) {
    unsigned vp = hp[j], vg = hg[j];
    if (vp) atomicAdd(&predRaw[b * BINS + j], vp);
    if (vg) atomicAdd(&gtRaw[b * BINS + j], vg);
  }
}

// ---------- kernel 3: normalize hists, KL term, final scalar ----------
__global__ __launch_bounds__(1024) void finalize_k(
    const unsigned* __restrict__ predRaw, const unsigned* __restrict__ gtRaw,
    const float* __restrict__ we2, const double* __restrict__ partaSum,
    float* __restrict__ out) {
  __shared__ double swp[16], swg[16];
  __shared__ double bc[2];
  const int tid = threadIdx.x;
  const int wave = tid >> 6, lane = tid & 63;
  const int M = BB * BINS;  // 16384
  const double invq = 1.0 / (double)QONE;

  double sp = 0.0, sg = 0.0;
  for (int i = tid; i < M; i += 1024) {
    sp += (double)predRaw[i];
    sg += (double)gtRaw[i];
  }
  sp = wred_sumd(sp);
  sg = wred_sumd(sg);
  if (lane == 0) { swp[wave] = sp; swg[wave] = sg; }
  __syncthreads();
  if (tid == 0) {
    double a = 0.0, b = 0.0;
    #pragma unroll
    for (int i = 0; i < 16; ++i) { a += swp[i]; b += swg[i]; }
    bc[0] = a; bc[1] = b;     // sums in fixed-point units (scale cancels)
  }
  __syncthreads();
  const float sumP = (float)(bc[0] * invq);
  const float sumG = (float)(bc[1] * invq);

  double pb = 0.0;
  for (int i = tid; i < M; i += 1024) {
    float p = (float)((double)predRaw[i] * invq) / sumP;
    float g = (float)((double)gtRaw[i] * invq) / sumG;
    float kld = fabsf(expf(g) * (g - p));
    float w2v = we2[i] + EPSF;
    pb += (double)(kld * w2v + kld / w2v);
  }
  pb = wred_sumd(pb);
  if (lane == 0) swp[wave] = pb;
  __syncthreads();
  if (tid == 0) {
    double s = 0.0;
    #pragma unroll
    for (int i = 0; i < 16; ++i) s += swp[i];
    double parta = partaSum[0] / (double)NTOT;
    double partb = s / (double)M;
    out[0] = (float)(4.0 * parta + partb);
  }
}

extern "C" void kernel_launch(void* const* d_in, const int* in_sizes, int n_in,
                              void* d_out, int out_size, void* d_ws, size_t ws_size,
                              hipStream_t stream) {
  const float* inputo = (const float*)d_in[0];
  const float* target = (const float*)d_in[1];
  const float* we1    = (const float*)d_in[2];
  const float* we2    = (const float*)d_in[3];
  float* out = (float*)d_out;

  char* ws = (char*)d_ws;
  float*     bounds   = (float*)ws;                      // 4 x f32
  double*    partaSum = (double*)(ws + 16);              // 1 x f64
  unsigned*  predRaw  = (unsigned*)(ws + 64);            // BB*BINS u32
  unsigned*  gtRaw    = (unsigned*)(ws + 64 + BB * BINS * 4);
  P1Partial* partials = (P1Partial*)(ws + 64 + 2 * BB * BINS * 4 + 64); // 64B-aligned

  init_ws<<<64, 256, 0, stream>>>(predRaw);  // hists contiguous (pred+gt)

  pass1<<<P1_BLOCKS, 256, 0, stream>>>((const float4*)inputo, (const float4*)target,
                                       (const f4v*)we1, partials);

  reduce_p1<<<1, 1024, 0, stream>>>(partials, bounds, partaSum);

  dim3 g2(256, BB);
  hist_pass<<<g2, 256, 0, stream>>>((const float4*)inputo, (const float4*)target,
                                    bounds, predRaw, gtRaw);

  finalize_k<<<1, 1024, 0, stream>>>(predRaw, gtRaw, we2, partaSum, out);
}